// Round 4
// baseline (52.001 us; speedup 1.0000x reference)
//
#include <hip/hip_runtime.h>

#define QN 32768
#define GN 64
#define BSN 16
#define KM 4
#define GPB 4
#define NTHREADS 1024
#define NWAVES (NTHREADS / 64)
#define NLISTS (GPB * 2)

// Branchless insert of key k into ascending sorted-4 list m (keep 4 smallest).
// 7 x v_min_f64/v_max_f64, no branches, no compares.
__device__ __forceinline__ void ins4(double* m, double k) {
    double t0 = fmin(m[0], k);  double h0 = fmax(m[0], k);
    double t1 = fmin(m[1], h0); double h1 = fmax(m[1], h0);
    double t2 = fmin(m[2], h1); double h2 = fmax(m[2], h1);
    double t3 = fmin(m[3], h2);
    m[0] = t0; m[1] = t1; m[2] = t2; m[3] = t3;
}

// a <- lowest-4 of merge(a, b), both ascending sorted-4. Bitonic, 12 minmax.
__device__ __forceinline__ void merge4s(double* a, const double* b) {
    double m0 = fmin(a[0], b[3]);
    double m1 = fmin(a[1], b[2]);
    double m2 = fmin(a[2], b[1]);
    double m3 = fmin(a[3], b[0]);
    double x0 = fmin(m0, m2), x2 = fmax(m0, m2);
    double x1 = fmin(m1, m3), x3 = fmax(m1, m3);
    a[0] = fmin(x0, x1); a[1] = fmax(x0, x1);
    a[2] = fmin(x2, x3); a[3] = fmax(x2, x3);
}

// key = float_bits(cost) * 2^15 + q  (exact integer < 2^46 in f64).
// cost >= 0 so float bits are order-preserving; lex (cost, q) order; q = key & 32767.
__device__ __forceinline__ double mkkey(float c, double qd) {
    return (double)__float_as_uint(c) * 32768.0 + qd;
}

__device__ __forceinline__ void evalq(double m[NLISTS][KM],
    const float* gcx, const float* gcy, const float* gww, const float* ghh,
    float4 p, float4 a, double qd)
{
    float pcx = (p.x + p.z) * 0.5f, pcy = (p.y + p.w) * 0.5f;
    float pw  = p.z - p.x,          ph  = p.w - p.y;
    float acx = (a.x + a.z) * 0.5f, acy = (a.y + a.w) * 0.5f;
    float aw  = a.z - a.x,          ah  = a.w - a.y;
#pragma unroll
    for (int gl = 0; gl < GPB; ++gl) {
        // reference sum order: ((|dcx|+|dcy|)+|dw|)+|dh|
        float cb = ((fabsf(pcx - gcx[gl]) + fabsf(pcy - gcy[gl]))
                    + fabsf(pw - gww[gl])) + fabsf(ph - ghh[gl]);
        ins4(m[gl * 2 + 0], mkkey(cb, qd));
        float ca = ((fabsf(acx - gcx[gl]) + fabsf(acy - gcy[gl]))
                    + fabsf(aw - gww[gl])) + fabsf(ah - ghh[gl]);
        ins4(m[gl * 2 + 1], mkkey(ca, qd));
    }
}

__global__ __launch_bounds__(NTHREADS)
__attribute__((amdgpu_waves_per_eu(4, 4)))   // pin 4 waves/EU (16/CU): VGPR budget
void UniformMatcher_kernel(                   // up to 128 -> no spill of the 64-reg
    const float4* __restrict__ pred,          // f64 key array (round-3: VGPR=64,
    const float4* __restrict__ anc,           // 6 MB spill writes)
    const float4* __restrict__ gt, int* __restrict__ out)
{
    // XCD swizzle: linear block id round-robins over 8 XCDs;
    // 2 batches per XCD so the 4 MB working set fits its private L2.
    int bid = blockIdx.x;
    int xcd = bid & 7;
    int k   = bid >> 3;                 // 0..31
    int b   = (xcd << 1) | (k & 1);     // 0..15
    int gc  = k >> 1;                   // 0..15

    int tid = threadIdx.x;

    float gcx[GPB], gcy[GPB], gww[GPB], ghh[GPB];
#pragma unroll
    for (int gl = 0; gl < GPB; ++gl) {
        float4 gb = gt[b * GN + gc * GPB + gl];
        gcx[gl] = (gb.x + gb.z) * 0.5f;
        gcy[gl] = (gb.y + gb.w) * 0.5f;
        gww[gl] = gb.z - gb.x;
        ghh[gl] = gb.w - gb.y;
    }

    double m[NLISTS][KM];
#pragma unroll
    for (int l = 0; l < NLISTS; ++l)
#pragma unroll
        for (int s = 0; s < KM; ++s) m[l][s] = __builtin_inf();

    const float4* pb = pred + (size_t)b * QN;
    const float4* ab = anc  + (size_t)b * QN;

    // 32 q per thread; 2x unrolled for load ILP
    for (int q = tid; q < QN; q += 2 * NTHREADS) {
        float4 p0 = pb[q];
        float4 a0 = ab[q];
        float4 p1 = pb[q + NTHREADS];
        float4 a1 = ab[q + NTHREADS];
        evalq(m, gcx, gcy, gww, ghh, p0, a0, (double)q);
        evalq(m, gcx, gcy, gww, ghh, p1, a1, (double)(q + NTHREADS));
    }

    // wave-64 butterfly: all lanes converge to identical sorted top-4
    for (int off = 1; off < 64; off <<= 1) {
#pragma unroll
        for (int l = 0; l < NLISTS; ++l) {
            double bb[KM];
#pragma unroll
            for (int s = 0; s < KM; ++s) bb[s] = __shfl_xor(m[l][s], off, 64);
            merge4s(m[l], bb);
        }
    }

    __shared__ double smem[NLISTS][NWAVES][KM];   // 4 KB
    int lane = tid & 63, wv = tid >> 6;
    if (lane == 0) {
#pragma unroll
        for (int l = 0; l < NLISTS; ++l)
#pragma unroll
            for (int s = 0; s < KM; ++s) smem[l][wv][s] = m[l][s];
    }
    __syncthreads();

    if (tid < NLISTS) {
        int l = tid;
        double r[KM];
#pragma unroll
        for (int s = 0; s < KM; ++s) r[s] = smem[l][0][s];
        for (int w = 1; w < NWAVES; ++w) {
            double bb[KM];
#pragma unroll
            for (int s = 0; s < KM; ++s) bb[s] = smem[l][w][s];
            merge4s(r, bb);
        }
        int gl = l >> 1, type = l & 1;
        int g = gc * GPB + gl;
        int base = b * (2 * KM * GN);
        int* out_j = out + BSN * 2 * KM * GN;
#pragma unroll
        for (int mm = 0; mm < KM; ++mm) {
            int qi = (int)((unsigned long long)r[mm] & 32767ull);
            // idx_i layout: [b, m, type, g] -> b*512 + m*128 + type*64 + g
            int pos = base + mm * (2 * GN) + type * GN + g;
            out[pos]   = qi;
            out_j[pos] = g;
        }
    }
}

extern "C" void kernel_launch(void* const* d_in, const int* in_sizes, int n_in,
                              void* d_out, int out_size, void* d_ws, size_t ws_size,
                              hipStream_t stream) {
    const float4* pred = (const float4*)d_in[0];
    const float4* anc  = (const float4*)d_in[1];
    const float4* gt   = (const float4*)d_in[2];
    int* out = (int*)d_out;
    dim3 grid(BSN * (GN / GPB));   // 256 blocks
    UniformMatcher_kernel<<<grid, NTHREADS, 0, stream>>>(pred, anc, gt, out);
}